// Round 3
// baseline (2810.992 us; speedup 1.0000x reference)
//
#include <hip/hip_runtime.h>

#define N_NODES 100000
#define N_EDGES 1600000
#define HID 128
#define NUM_LAYERS 10
#define NUM_GRAPHS 64
#define SCAN_BLOCKS ((N_NODES + 255) / 256)

// ---------------- CSR build ----------------

__global__ __launch_bounds__(256) void count_deg_kernel(const int* __restrict__ dst,
                                                        int* __restrict__ deg, int E) {
  int e = blockIdx.x * 256 + threadIdx.x;
  if (e < E) atomicAdd(&deg[dst[e]], 1);
}

// per-block sums of deg
__global__ __launch_bounds__(256) void block_sum_kernel(const int* __restrict__ deg,
                                                        int* __restrict__ psum, int n) {
  __shared__ int sd[256];
  int i = blockIdx.x * 256 + threadIdx.x;
  sd[threadIdx.x] = (i < n) ? deg[i] : 0;
  __syncthreads();
  for (int off = 128; off > 0; off >>= 1) {
    if (threadIdx.x < off) sd[threadIdx.x] += sd[threadIdx.x + off];
    __syncthreads();
  }
  if (threadIdx.x == 0) psum[blockIdx.x] = sd[0];
}

// exclusive scan of psum[SCAN_BLOCKS] (<=512) in one block
__global__ __launch_bounds__(512) void scan_partials_kernel(const int* __restrict__ psum,
                                                            int* __restrict__ poff, int nb) {
  __shared__ int sd[512];
  int i = threadIdx.x;
  int v = (i < nb) ? psum[i] : 0;
  sd[i] = v;
  __syncthreads();
  for (int off = 1; off < 512; off <<= 1) {
    int t = (i >= off) ? sd[i - off] : 0;
    __syncthreads();
    sd[i] += t;
    __syncthreads();
  }
  if (i < nb) poff[i] = sd[i] - v;  // exclusive
}

// rs[i+1] = poff[b] + incl_scan(deg)[i]; rs[0]=0; cur[i] = exclusive start
__global__ __launch_bounds__(256) void write_rs_kernel(const int* __restrict__ deg,
                                                       const int* __restrict__ poff,
                                                       int* __restrict__ rs,
                                                       int* __restrict__ cur, int n) {
  __shared__ int sd[256];
  int i = blockIdx.x * 256 + threadIdx.x;
  int v = (i < n) ? deg[i] : 0;
  sd[threadIdx.x] = v;
  __syncthreads();
  for (int off = 1; off < 256; off <<= 1) {
    int t = (threadIdx.x >= off) ? sd[threadIdx.x - off] : 0;
    __syncthreads();
    sd[threadIdx.x] += t;
    __syncthreads();
  }
  if (i < n) {
    int incl = poff[blockIdx.x] + sd[threadIdx.x];
    rs[i + 1] = incl;
    cur[i] = incl - v;  // exclusive prefix = CSR start
  }
  if (i == 0) rs[0] = 0;
}

__global__ __launch_bounds__(256) void fill_csr_kernel(const int* __restrict__ src,
                                                       const int* __restrict__ dst,
                                                       int* __restrict__ cur,
                                                       int* __restrict__ csr, int E) {
  int e = blockIdx.x * 256 + threadIdx.x;
  if (e < E) {
    int p = atomicAdd(&cur[dst[e]], 1);
    csr[p] = src[e];
  }
}

// ---------------- fused layer: gather + MLP ----------------
// xout = relu( relu(h@W1+b1)@W2 + b2 [+h] ) + xin,  h = (1+eps)*xin + sum_{u->v} xin[u]
// 64 rows per 256-thread block, 5 blocks/CU (LDS 5*32KB = 160KB).
// Gather: 32 lanes/node, software-pipelined 4 edges deep.

__global__ __launch_bounds__(256, 5) void layer_kernel(const float* __restrict__ xin,
                                                       float* __restrict__ xout,
                                                       const int* __restrict__ rs,
                                                       const int* __restrict__ csr,
                                                       const float* __restrict__ eps, int layer,
                                                       const float* __restrict__ W1,
                                                       const float* __restrict__ b1,
                                                       const float* __restrict__ W2,
                                                       const float* __restrict__ b2,
                                                       int n, int addH) {
  __shared__ float lh[64 * 128];
  const int tid = threadIdx.x;
  const int row0 = blockIdx.x * 64;
  const float4* x4 = (const float4*)xin;
  float4* lh4 = (float4*)lh;
  const float s = 1.0f + eps[layer];

  // ---- Phase 1: gather h-tile into LDS. 8 nodes at a time, 32 lanes/node.
  const int w = tid >> 5;
  const int lane = tid & 31;
#pragma unroll
  for (int it = 0; it < 8; ++it) {
    int li = it * 8 + w;          // local row 0..63
    int node = row0 + li;
    float ax = 0.f, ay = 0.f, az = 0.f, aw = 0.f;
    if (node < n) {
      float4 v = x4[node * 32 + lane];
      ax = v.x * s; ay = v.y * s; az = v.z * s; aw = v.w * s;
      const int e0 = rs[node];
      const int m = rs[node + 1] - e0;
      int i = 0;
      if (m >= 4) {
        int u0 = csr[e0], u1 = csr[e0 + 1], u2 = csr[e0 + 2], u3 = csr[e0 + 3];
        for (; i + 8 <= m; i += 4) {
          float4 t0 = x4[u0 * 32 + lane];
          float4 t1 = x4[u1 * 32 + lane];
          float4 t2 = x4[u2 * 32 + lane];
          float4 t3 = x4[u3 * 32 + lane];
          // prefetch next quad of indices before consuming rows
          u0 = csr[e0 + i + 4]; u1 = csr[e0 + i + 5];
          u2 = csr[e0 + i + 6]; u3 = csr[e0 + i + 7];
          ax += t0.x + t1.x + t2.x + t3.x;
          ay += t0.y + t1.y + t2.y + t3.y;
          az += t0.z + t1.z + t2.z + t3.z;
          aw += t0.w + t1.w + t2.w + t3.w;
        }
        // consume last preloaded quad
        {
          float4 t0 = x4[u0 * 32 + lane];
          float4 t1 = x4[u1 * 32 + lane];
          float4 t2 = x4[u2 * 32 + lane];
          float4 t3 = x4[u3 * 32 + lane];
          ax += t0.x + t1.x + t2.x + t3.x;
          ay += t0.y + t1.y + t2.y + t3.y;
          az += t0.z + t1.z + t2.z + t3.z;
          aw += t0.w + t1.w + t2.w + t3.w;
          i += 4;
        }
      }
      for (; i < m; ++i) {
        int u = csr[e0 + i];
        float4 t = x4[u * 32 + lane];
        ax += t.x; ay += t.y; az += t.z; aw += t.w;
      }
    }
    float4 r; r.x = ax; r.y = ay; r.z = az; r.w = aw;
    lh4[li * 32 + lane] = r;
  }
  __syncthreads();

  // ---- Phase 2: GEMM1 (mid = relu(h@W1+b1))
  const int cg = tid & 31;
  const int rg = tid >> 5;
  float acc[8][4];
#pragma unroll
  for (int r = 0; r < 8; ++r) { acc[r][0] = acc[r][1] = acc[r][2] = acc[r][3] = 0.f; }

  for (int k4 = 0; k4 < 32; ++k4) {
    float4 w0 = *(const float4*)(W1 + (k4 * 4 + 0) * 128 + cg * 4);
    float4 w1 = *(const float4*)(W1 + (k4 * 4 + 1) * 128 + cg * 4);
    float4 w2 = *(const float4*)(W1 + (k4 * 4 + 2) * 128 + cg * 4);
    float4 w3 = *(const float4*)(W1 + (k4 * 4 + 3) * 128 + cg * 4);
#pragma unroll
    for (int r = 0; r < 8; ++r) {
      float4 a = *(const float4*)(lh + (rg * 8 + r) * 128 + k4 * 4);
      acc[r][0] += a.x * w0.x + a.y * w1.x + a.z * w2.x + a.w * w3.x;
      acc[r][1] += a.x * w0.y + a.y * w1.y + a.z * w2.y + a.w * w3.y;
      acc[r][2] += a.x * w0.z + a.y * w1.z + a.z * w2.z + a.w * w3.z;
      acc[r][3] += a.x * w0.w + a.y * w1.w + a.z * w2.w + a.w * w3.w;
    }
  }

  // snapshot h values needed in epilogue (before lh is overwritten by mid)
  float4 hreg[8];
#pragma unroll
  for (int r = 0; r < 8; ++r) hreg[r] = *(const float4*)(lh + (rg * 8 + r) * 128 + cg * 4);
  __syncthreads();  // everyone done reading h

  {
    float4 bb = *(const float4*)(b1 + cg * 4);
#pragma unroll
    for (int r = 0; r < 8; ++r) {
      float4 o;
      o.x = fmaxf(acc[r][0] + bb.x, 0.f);
      o.y = fmaxf(acc[r][1] + bb.y, 0.f);
      o.z = fmaxf(acc[r][2] + bb.z, 0.f);
      o.w = fmaxf(acc[r][3] + bb.w, 0.f);
      *(float4*)(lh + (rg * 8 + r) * 128 + cg * 4) = o;
      acc[r][0] = acc[r][1] = acc[r][2] = acc[r][3] = 0.f;
    }
  }
  __syncthreads();

  // ---- Phase 3: GEMM2 (out = mid@W2 + b2)
  for (int k4 = 0; k4 < 32; ++k4) {
    float4 w0 = *(const float4*)(W2 + (k4 * 4 + 0) * 128 + cg * 4);
    float4 w1 = *(const float4*)(W2 + (k4 * 4 + 1) * 128 + cg * 4);
    float4 w2 = *(const float4*)(W2 + (k4 * 4 + 2) * 128 + cg * 4);
    float4 w3 = *(const float4*)(W2 + (k4 * 4 + 3) * 128 + cg * 4);
#pragma unroll
    for (int r = 0; r < 8; ++r) {
      float4 a = *(const float4*)(lh + (rg * 8 + r) * 128 + k4 * 4);
      acc[r][0] += a.x * w0.x + a.y * w1.x + a.z * w2.x + a.w * w3.x;
      acc[r][1] += a.x * w0.y + a.y * w1.y + a.z * w2.y + a.w * w3.y;
      acc[r][2] += a.x * w0.z + a.y * w1.z + a.z * w2.z + a.w * w3.z;
      acc[r][3] += a.x * w0.w + a.y * w1.w + a.z * w2.w + a.w * w3.w;
    }
  }

  // ---- Epilogue: +b2 (+h) -> relu -> +xin, write xout
  float4 b2v = *(const float4*)(b2 + cg * 4);
  float4* xo4 = (float4*)xout;
#pragma unroll
  for (int r = 0; r < 8; ++r) {
    int row = row0 + rg * 8 + r;
    if (row < n) {
      float ox = acc[r][0] + b2v.x;
      float oy = acc[r][1] + b2v.y;
      float oz = acc[r][2] + b2v.z;
      float ow = acc[r][3] + b2v.w;
      if (addH) {
        ox += hreg[r].x; oy += hreg[r].y; oz += hreg[r].z; ow += hreg[r].w;
      }
      ox = fmaxf(ox, 0.f); oy = fmaxf(oy, 0.f); oz = fmaxf(oz, 0.f); ow = fmaxf(ow, 0.f);
      float4 xv = x4[row * 32 + cg];
      float4 o;
      o.x = ox + xv.x; o.y = oy + xv.y; o.z = oz + xv.z; o.w = ow + xv.w;
      xo4[row * 32 + cg] = o;
    }
  }
}

// ---------------- pooling (batch is sorted) ----------------

__global__ __launch_bounds__(128) void pool_kernel(const float* __restrict__ x,
                                                   const int* __restrict__ batch,
                                                   float* __restrict__ pool,
                                                   int* __restrict__ gcnt, int n) {
  const int CH = 512;
  int c = threadIdx.x;
  int n0 = blockIdx.x * CH;
  if (n0 >= n) return;
  int n1 = n0 + CH; if (n1 > n) n1 = n;
  float acc = 0.f;
  int g = batch[n0];
  int cl = 0;
  for (int i = n0; i < n1; ++i) {
    int gi = batch[i];
    if (gi != g) {
      atomicAdd(&pool[g * 128 + c], acc);
      if (c == 0) atomicAdd(&gcnt[g], cl);
      acc = 0.f; cl = 0; g = gi;
    }
    acc += x[i * 128 + c];
    cl++;
  }
  atomicAdd(&pool[g * 128 + c], acc);
  if (c == 0) atomicAdd(&gcnt[g], cl);
}

// ---------------- classifier: one block per graph ----------------

__global__ __launch_bounds__(128) void classifier_kernel(const float* __restrict__ pool,
                                                         const int* __restrict__ gcnt,
                                                         const float* __restrict__ Wc1,
                                                         const float* __restrict__ bc1,
                                                         const float* __restrict__ Wc2,
                                                         const float* __restrict__ bc2,
                                                         float* __restrict__ out) {
  __shared__ float prow[128];
  __shared__ float hid[128];
  int g = blockIdx.x;
  int c = threadIdx.x;
  float cf = (float)gcnt[g];
  if (cf < 1.f) cf = 1.f;
  prow[c] = pool[g * 128 + c] / cf;
  __syncthreads();
  float a = bc1[c];
  for (int k = 0; k < 128; ++k) a += prow[k] * Wc1[k * 128 + c];
  hid[c] = fmaxf(a, 0.f);
  __syncthreads();
  if (c < 2) {
    float a2 = bc2[c];
    for (int k = 0; k < 128; ++k) a2 += hid[k] * Wc2[k * 2 + c];
    out[g * 2 + c] = a2;
  }
}

// ---------------- launch ----------------

extern "C" void kernel_launch(void* const* d_in, const int* in_sizes, int n_in,
                              void* d_out, int out_size, void* d_ws, size_t ws_size,
                              hipStream_t stream) {
  const float* x_in = (const float*)d_in[0];
  const int* edge_index = (const int*)d_in[1];
  const int* batch = (const int*)d_in[2];
  const float* eps = (const float*)d_in[3];
  const float* W1 = (const float*)d_in[4];
  const float* b1 = (const float*)d_in[5];
  const float* W2 = (const float*)d_in[6];
  const float* b2 = (const float*)d_in[7];
  const float* Wc1 = (const float*)d_in[8];
  const float* bc1 = (const float*)d_in[9];
  const float* Wc2 = (const float*)d_in[10];
  const float* bc2 = (const float*)d_in[11];
  float* out = (float*)d_out;

  const int N = N_NODES, E = N_EDGES;
  const int* src = edge_index;
  const int* dst = edge_index + E;

  // workspace layout
  float* xa = (float*)d_ws;                    // N*128 floats
  float* xb = xa + (size_t)N * 128;            // N*128 floats
  int* deg = (int*)(xb + (size_t)N * 128);     // N
  int* rs = deg + N;                           // N+1
  int* cur = rs + (N + 1);                     // N
  int* csr = cur + N;                          // E
  float* pool = (float*)(csr + E);             // 64*128
  int* gcnt = (int*)(pool + NUM_GRAPHS * 128); // 64
  int* psum = gcnt + NUM_GRAPHS;               // SCAN_BLOCKS
  int* poff = psum + SCAN_BLOCKS;              // SCAN_BLOCKS

  hipMemsetAsync(deg, 0, N * sizeof(int), stream);

  // CSR build
  count_deg_kernel<<<(E + 255) / 256, 256, 0, stream>>>(dst, deg, E);
  block_sum_kernel<<<SCAN_BLOCKS, 256, 0, stream>>>(deg, psum, N);
  scan_partials_kernel<<<1, 512, 0, stream>>>(psum, poff, SCAN_BLOCKS);
  write_rs_kernel<<<SCAN_BLOCKS, 256, 0, stream>>>(deg, poff, rs, cur, N);
  fill_csr_kernel<<<(E + 255) / 256, 256, 0, stream>>>(src, dst, cur, csr, E);

  // layers (ping-pong; layer 0 reads the input buffer directly)
  for (int i = 0; i < NUM_LAYERS; ++i) {
    const float* xi = (i == 0) ? x_in : ((i % 2 == 0) ? xb : xa);
    float* xo = (i % 2 == 0) ? xa : xb;
    layer_kernel<<<(N + 63) / 64, 256, 0, stream>>>(xi, xo, rs, csr, eps, i,
                                                    W1 + (size_t)i * 128 * 128, b1 + (size_t)i * 128,
                                                    W2 + (size_t)i * 128 * 128, b2 + (size_t)i * 128,
                                                    N, i > 0 ? 1 : 0);
  }
  const float* xfin = (NUM_LAYERS % 2 == 0) ? xb : xa;

  // pooling + classifier
  hipMemsetAsync(pool, 0, NUM_GRAPHS * 128 * sizeof(float), stream);
  hipMemsetAsync(gcnt, 0, NUM_GRAPHS * sizeof(int), stream);
  pool_kernel<<<(N + 511) / 512, 128, 0, stream>>>(xfin, batch, pool, gcnt, N);
  classifier_kernel<<<NUM_GRAPHS, 128, 0, stream>>>(pool, gcnt, Wc1, bc1, Wc2, bc2, out);
}

// Round 4
// 2548.045 us; speedup vs baseline: 1.1032x; 1.1032x over previous
//
#include <hip/hip_runtime.h>

#define N_NODES 100000
#define N_EDGES 1600000
#define HID 128
#define NUM_LAYERS 10
#define NUM_GRAPHS 64
#define SCAN_BLOCKS ((N_NODES + 255) / 256)
#define IDX_CAP 2048   // LDS-staged neighbor indices per 64-node block (mean 1024, sigma 32)

// ---------------- CSR build ----------------

__global__ __launch_bounds__(256) void count_deg_kernel(const int* __restrict__ dst,
                                                        int* __restrict__ deg, int E) {
  int e = blockIdx.x * 256 + threadIdx.x;
  if (e < E) atomicAdd(&deg[dst[e]], 1);
}

__global__ __launch_bounds__(256) void block_sum_kernel(const int* __restrict__ deg,
                                                        int* __restrict__ psum, int n) {
  __shared__ int sd[256];
  int i = blockIdx.x * 256 + threadIdx.x;
  sd[threadIdx.x] = (i < n) ? deg[i] : 0;
  __syncthreads();
  for (int off = 128; off > 0; off >>= 1) {
    if (threadIdx.x < off) sd[threadIdx.x] += sd[threadIdx.x + off];
    __syncthreads();
  }
  if (threadIdx.x == 0) psum[blockIdx.x] = sd[0];
}

__global__ __launch_bounds__(512) void scan_partials_kernel(const int* __restrict__ psum,
                                                            int* __restrict__ poff, int nb) {
  __shared__ int sd[512];
  int i = threadIdx.x;
  int v = (i < nb) ? psum[i] : 0;
  sd[i] = v;
  __syncthreads();
  for (int off = 1; off < 512; off <<= 1) {
    int t = (i >= off) ? sd[i - off] : 0;
    __syncthreads();
    sd[i] += t;
    __syncthreads();
  }
  if (i < nb) poff[i] = sd[i] - v;  // exclusive
}

__global__ __launch_bounds__(256) void write_rs_kernel(const int* __restrict__ deg,
                                                       const int* __restrict__ poff,
                                                       int* __restrict__ rs,
                                                       int* __restrict__ cur, int n) {
  __shared__ int sd[256];
  int i = blockIdx.x * 256 + threadIdx.x;
  int v = (i < n) ? deg[i] : 0;
  sd[threadIdx.x] = v;
  __syncthreads();
  for (int off = 1; off < 256; off <<= 1) {
    int t = (threadIdx.x >= off) ? sd[threadIdx.x - off] : 0;
    __syncthreads();
    sd[threadIdx.x] += t;
    __syncthreads();
  }
  if (i < n) {
    int incl = poff[blockIdx.x] + sd[threadIdx.x];
    rs[i + 1] = incl;
    cur[i] = incl - v;
  }
  if (i == 0) rs[0] = 0;
}

__global__ __launch_bounds__(256) void fill_csr_kernel(const int* __restrict__ src,
                                                       const int* __restrict__ dst,
                                                       int* __restrict__ cur,
                                                       int* __restrict__ csr, int E) {
  int e = blockIdx.x * 256 + threadIdx.x;
  if (e < E) {
    int p = atomicAdd(&cur[dst[e]], 1);
    csr[p] = src[e];
  }
}

// ---------------- fused layer: gather + MLP ----------------
// xout = relu( relu(h@W1+b1)@W2 + b2 [+h] ) + xin,  h = (1+eps)*xin + sum_{u->v} xin[u]
// 64 rows per 256-thread block. Neighbor indices staged in LDS first (coalesced,
// contiguous CSR range) so the row-gather pipeline has NO vm-queue index dependence:
// 8 row loads in flight per worker, rolling vmcnt waits, no per-iteration drain.

__global__ __launch_bounds__(256, 4) void layer_kernel(const float* __restrict__ xin,
                                                       float* __restrict__ xout,
                                                       const int* __restrict__ rs,
                                                       const int* __restrict__ csr,
                                                       const float* __restrict__ eps, int layer,
                                                       const float* __restrict__ W1,
                                                       const float* __restrict__ b1,
                                                       const float* __restrict__ W2,
                                                       const float* __restrict__ b2,
                                                       int n, int addH) {
  __shared__ float lh[64 * 128];
  __shared__ int lidx[IDX_CAP];
  const int tid = threadIdx.x;
  const int row0 = blockIdx.x * 64;
  const float4* x4 = (const float4*)xin;
  float4* lh4 = (float4*)lh;
  const float s = 1.0f + eps[layer];

  // ---- Phase 0: stage this block's CSR index range into LDS (coalesced).
  int rowEnd = row0 + 64; if (rowEnd > n) rowEnd = n;
  const int eBase = rs[row0];
  const int cnt = rs[rowEnd] - eBase;
  const int stage = (cnt < IDX_CAP) ? cnt : IDX_CAP;
  for (int t = tid; t < stage; t += 256) lidx[t] = csr[eBase + t];
  __syncthreads();

  // ---- Phase 1: gather h-tile into LDS. 8 nodes at a time, 32 lanes/node.
  const int w = tid >> 5;
  const int lane = tid & 31;
#pragma unroll
  for (int it = 0; it < 8; ++it) {
    int li = it * 8 + w;          // local row 0..63
    int node = row0 + li;
    float ax = 0.f, ay = 0.f, az = 0.f, aw = 0.f;
    if (node < n) {
      float4 v = x4[node * 32 + lane];
      ax = v.x * s; ay = v.y * s; az = v.z * s; aw = v.w * s;
      const int e0 = rs[node];
      const int m = rs[node + 1] - e0;
      const int lb = e0 - eBase;
      int i = 0;
      if (lb + m <= stage) {
        // fast path: all indices in LDS
        for (; i + 8 <= m; i += 8) {
          int u0 = lidx[lb + i + 0], u1 = lidx[lb + i + 1];
          int u2 = lidx[lb + i + 2], u3 = lidx[lb + i + 3];
          int u4 = lidx[lb + i + 4], u5 = lidx[lb + i + 5];
          int u6 = lidx[lb + i + 6], u7 = lidx[lb + i + 7];
          float4 t0 = x4[u0 * 32 + lane];
          float4 t1 = x4[u1 * 32 + lane];
          float4 t2 = x4[u2 * 32 + lane];
          float4 t3 = x4[u3 * 32 + lane];
          float4 t4 = x4[u4 * 32 + lane];
          float4 t5 = x4[u5 * 32 + lane];
          float4 t6 = x4[u6 * 32 + lane];
          float4 t7 = x4[u7 * 32 + lane];
          ax += t0.x + t1.x + t2.x + t3.x + t4.x + t5.x + t6.x + t7.x;
          ay += t0.y + t1.y + t2.y + t3.y + t4.y + t5.y + t6.y + t7.y;
          az += t0.z + t1.z + t2.z + t3.z + t4.z + t5.z + t6.z + t7.z;
          aw += t0.w + t1.w + t2.w + t3.w + t4.w + t5.w + t6.w + t7.w;
        }
        if (i + 4 <= m) {
          int u0 = lidx[lb + i + 0], u1 = lidx[lb + i + 1];
          int u2 = lidx[lb + i + 2], u3 = lidx[lb + i + 3];
          float4 t0 = x4[u0 * 32 + lane];
          float4 t1 = x4[u1 * 32 + lane];
          float4 t2 = x4[u2 * 32 + lane];
          float4 t3 = x4[u3 * 32 + lane];
          ax += t0.x + t1.x + t2.x + t3.x;
          ay += t0.y + t1.y + t2.y + t3.y;
          az += t0.z + t1.z + t2.z + t3.z;
          aw += t0.w + t1.w + t2.w + t3.w;
          i += 4;
        }
        if (i + 2 <= m) {
          int u0 = lidx[lb + i + 0], u1 = lidx[lb + i + 1];
          float4 t0 = x4[u0 * 32 + lane];
          float4 t1 = x4[u1 * 32 + lane];
          ax += t0.x + t1.x; ay += t0.y + t1.y;
          az += t0.z + t1.z; aw += t0.w + t1.w;
          i += 2;
        }
        if (i < m) {
          int u = lidx[lb + i];
          float4 t = x4[u * 32 + lane];
          ax += t.x; ay += t.y; az += t.z; aw += t.w;
        }
      } else {
        // slow fallback (never taken for this input's degree distribution)
        for (; i < m; ++i) {
          int u = csr[e0 + i];
          float4 t = x4[u * 32 + lane];
          ax += t.x; ay += t.y; az += t.z; aw += t.w;
        }
      }
    }
    float4 r; r.x = ax; r.y = ay; r.z = az; r.w = aw;
    lh4[li * 32 + lane] = r;
  }
  __syncthreads();

  // ---- Phase 2: GEMM1 (mid = relu(h@W1+b1))
  const int cg = tid & 31;
  const int rg = tid >> 5;
  float acc[8][4];
#pragma unroll
  for (int r = 0; r < 8; ++r) { acc[r][0] = acc[r][1] = acc[r][2] = acc[r][3] = 0.f; }

  for (int k4 = 0; k4 < 32; ++k4) {
    float4 w0 = *(const float4*)(W1 + (k4 * 4 + 0) * 128 + cg * 4);
    float4 w1 = *(const float4*)(W1 + (k4 * 4 + 1) * 128 + cg * 4);
    float4 w2 = *(const float4*)(W1 + (k4 * 4 + 2) * 128 + cg * 4);
    float4 w3 = *(const float4*)(W1 + (k4 * 4 + 3) * 128 + cg * 4);
#pragma unroll
    for (int r = 0; r < 8; ++r) {
      float4 a = *(const float4*)(lh + (rg * 8 + r) * 128 + k4 * 4);
      acc[r][0] += a.x * w0.x + a.y * w1.x + a.z * w2.x + a.w * w3.x;
      acc[r][1] += a.x * w0.y + a.y * w1.y + a.z * w2.y + a.w * w3.y;
      acc[r][2] += a.x * w0.z + a.y * w1.z + a.z * w2.z + a.w * w3.z;
      acc[r][3] += a.x * w0.w + a.y * w1.w + a.z * w2.w + a.w * w3.w;
    }
  }

  // snapshot h values needed in epilogue (before lh is overwritten by mid)
  float4 hreg[8];
#pragma unroll
  for (int r = 0; r < 8; ++r) hreg[r] = *(const float4*)(lh + (rg * 8 + r) * 128 + cg * 4);
  __syncthreads();

  {
    float4 bb = *(const float4*)(b1 + cg * 4);
#pragma unroll
    for (int r = 0; r < 8; ++r) {
      float4 o;
      o.x = fmaxf(acc[r][0] + bb.x, 0.f);
      o.y = fmaxf(acc[r][1] + bb.y, 0.f);
      o.z = fmaxf(acc[r][2] + bb.z, 0.f);
      o.w = fmaxf(acc[r][3] + bb.w, 0.f);
      *(float4*)(lh + (rg * 8 + r) * 128 + cg * 4) = o;
      acc[r][0] = acc[r][1] = acc[r][2] = acc[r][3] = 0.f;
    }
  }
  __syncthreads();

  // ---- Phase 3: GEMM2 (out = mid@W2 + b2)
  for (int k4 = 0; k4 < 32; ++k4) {
    float4 w0 = *(const float4*)(W2 + (k4 * 4 + 0) * 128 + cg * 4);
    float4 w1 = *(const float4*)(W2 + (k4 * 4 + 1) * 128 + cg * 4);
    float4 w2 = *(const float4*)(W2 + (k4 * 4 + 2) * 128 + cg * 4);
    float4 w3 = *(const float4*)(W2 + (k4 * 4 + 3) * 128 + cg * 4);
#pragma unroll
    for (int r = 0; r < 8; ++r) {
      float4 a = *(const float4*)(lh + (rg * 8 + r) * 128 + k4 * 4);
      acc[r][0] += a.x * w0.x + a.y * w1.x + a.z * w2.x + a.w * w3.x;
      acc[r][1] += a.x * w0.y + a.y * w1.y + a.z * w2.y + a.w * w3.y;
      acc[r][2] += a.x * w0.z + a.y * w1.z + a.z * w2.z + a.w * w3.z;
      acc[r][3] += a.x * w0.w + a.y * w1.w + a.z * w2.w + a.w * w3.w;
    }
  }

  // ---- Epilogue: +b2 (+h) -> relu -> +xin, write xout
  float4 b2v = *(const float4*)(b2 + cg * 4);
  float4* xo4 = (float4*)xout;
#pragma unroll
  for (int r = 0; r < 8; ++r) {
    int row = row0 + rg * 8 + r;
    if (row < n) {
      float ox = acc[r][0] + b2v.x;
      float oy = acc[r][1] + b2v.y;
      float oz = acc[r][2] + b2v.z;
      float ow = acc[r][3] + b2v.w;
      if (addH) {
        ox += hreg[r].x; oy += hreg[r].y; oz += hreg[r].z; ow += hreg[r].w;
      }
      ox = fmaxf(ox, 0.f); oy = fmaxf(oy, 0.f); oz = fmaxf(oz, 0.f); ow = fmaxf(ow, 0.f);
      float4 xv = x4[row * 32 + cg];
      float4 o;
      o.x = ox + xv.x; o.y = oy + xv.y; o.z = oz + xv.z; o.w = ow + xv.w;
      xo4[row * 32 + cg] = o;
    }
  }
}

// ---------------- pooling (batch is sorted) ----------------

__global__ __launch_bounds__(128) void pool_kernel(const float* __restrict__ x,
                                                   const int* __restrict__ batch,
                                                   float* __restrict__ pool,
                                                   int* __restrict__ gcnt, int n) {
  const int CH = 512;
  int c = threadIdx.x;
  int n0 = blockIdx.x * CH;
  if (n0 >= n) return;
  int n1 = n0 + CH; if (n1 > n) n1 = n;
  float acc = 0.f;
  int g = batch[n0];
  int cl = 0;
  for (int i = n0; i < n1; ++i) {
    int gi = batch[i];
    if (gi != g) {
      atomicAdd(&pool[g * 128 + c], acc);
      if (c == 0) atomicAdd(&gcnt[g], cl);
      acc = 0.f; cl = 0; g = gi;
    }
    acc += x[i * 128 + c];
    cl++;
  }
  atomicAdd(&pool[g * 128 + c], acc);
  if (c == 0) atomicAdd(&gcnt[g], cl);
}

// ---------------- classifier: one block per graph ----------------

__global__ __launch_bounds__(128) void classifier_kernel(const float* __restrict__ pool,
                                                         const int* __restrict__ gcnt,
                                                         const float* __restrict__ Wc1,
                                                         const float* __restrict__ bc1,
                                                         const float* __restrict__ Wc2,
                                                         const float* __restrict__ bc2,
                                                         float* __restrict__ out) {
  __shared__ float prow[128];
  __shared__ float hid[128];
  int g = blockIdx.x;
  int c = threadIdx.x;
  float cf = (float)gcnt[g];
  if (cf < 1.f) cf = 1.f;
  prow[c] = pool[g * 128 + c] / cf;
  __syncthreads();
  float a = bc1[c];
  for (int k = 0; k < 128; ++k) a += prow[k] * Wc1[k * 128 + c];
  hid[c] = fmaxf(a, 0.f);
  __syncthreads();
  if (c < 2) {
    float a2 = bc2[c];
    for (int k = 0; k < 128; ++k) a2 += hid[k] * Wc2[k * 2 + c];
    out[g * 2 + c] = a2;
  }
}

// ---------------- launch ----------------

extern "C" void kernel_launch(void* const* d_in, const int* in_sizes, int n_in,
                              void* d_out, int out_size, void* d_ws, size_t ws_size,
                              hipStream_t stream) {
  const float* x_in = (const float*)d_in[0];
  const int* edge_index = (const int*)d_in[1];
  const int* batch = (const int*)d_in[2];
  const float* eps = (const float*)d_in[3];
  const float* W1 = (const float*)d_in[4];
  const float* b1 = (const float*)d_in[5];
  const float* W2 = (const float*)d_in[6];
  const float* b2 = (const float*)d_in[7];
  const float* Wc1 = (const float*)d_in[8];
  const float* bc1 = (const float*)d_in[9];
  const float* Wc2 = (const float*)d_in[10];
  const float* bc2 = (const float*)d_in[11];
  float* out = (float*)d_out;

  const int N = N_NODES, E = N_EDGES;
  const int* src = edge_index;
  const int* dst = edge_index + E;

  // workspace layout
  float* xa = (float*)d_ws;                    // N*128 floats
  float* xb = xa + (size_t)N * 128;            // N*128 floats
  int* deg = (int*)(xb + (size_t)N * 128);     // N
  int* rs = deg + N;                           // N+1
  int* cur = rs + (N + 1);                     // N
  int* csr = cur + N;                          // E
  float* pool = (float*)(csr + E);             // 64*128
  int* gcnt = (int*)(pool + NUM_GRAPHS * 128); // 64
  int* psum = gcnt + NUM_GRAPHS;               // SCAN_BLOCKS
  int* poff = psum + SCAN_BLOCKS;              // SCAN_BLOCKS

  hipMemsetAsync(deg, 0, N * sizeof(int), stream);

  // CSR build
  count_deg_kernel<<<(E + 255) / 256, 256, 0, stream>>>(dst, deg, E);
  block_sum_kernel<<<SCAN_BLOCKS, 256, 0, stream>>>(deg, psum, N);
  scan_partials_kernel<<<1, 512, 0, stream>>>(psum, poff, SCAN_BLOCKS);
  write_rs_kernel<<<SCAN_BLOCKS, 256, 0, stream>>>(deg, poff, rs, cur, N);
  fill_csr_kernel<<<(E + 255) / 256, 256, 0, stream>>>(src, dst, cur, csr, E);

  // layers (ping-pong; layer 0 reads the input buffer directly)
  for (int i = 0; i < NUM_LAYERS; ++i) {
    const float* xi = (i == 0) ? x_in : ((i % 2 == 0) ? xb : xa);
    float* xo = (i % 2 == 0) ? xa : xb;
    layer_kernel<<<(N + 63) / 64, 256, 0, stream>>>(xi, xo, rs, csr, eps, i,
                                                    W1 + (size_t)i * 128 * 128, b1 + (size_t)i * 128,
                                                    W2 + (size_t)i * 128 * 128, b2 + (size_t)i * 128,
                                                    N, i > 0 ? 1 : 0);
  }
  const float* xfin = (NUM_LAYERS % 2 == 0) ? xb : xa;

  // pooling + classifier
  hipMemsetAsync(pool, 0, NUM_GRAPHS * 128 * sizeof(float), stream);
  hipMemsetAsync(gcnt, 0, NUM_GRAPHS * sizeof(int), stream);
  pool_kernel<<<(N + 511) / 512, 128, 0, stream>>>(xfin, batch, pool, gcnt, N);
  classifier_kernel<<<NUM_GRAPHS, 128, 0, stream>>>(pool, gcnt, Wc1, bc1, Wc2, bc2, out);
}